// Round 4
// baseline (171.075 us; speedup 1.0000x reference)
//
#include <hip/hip_runtime.h>

// Cost volume: B=4, C=32, H=256, W=256, D=9, G=8, cpg=4
// out[b,g,d,h,w] = mean_{c in group g} var(warp_l, warp_r, feat_ref)
//
// R5: float4 end-to-end. R1-R4 (four different structures) all pinned at
// 55-62us with identical FETCH/WRITE and VALUBusy ranging 33-80% => the
// shared trait is 4B/lane access granularity; service rate ~3.1 TB/s vs
// 6.3 TB/s float4 copy ceiling. This version moves the SAME bytes in
// 4x fewer requests:
//  - 1 thread = 4 consecutive pixels; 1 wave = 1 full row (64x4=256).
//  - All 13 loads and 9 stores are dwordx4 (16B/lane, 1KB/wave).
//  - No LDS, no barriers: the +/-2-pixel halo comes from neighbor lanes
//    via __shfl_up/down(.,1); wave-edge lanes coincide exactly with the
//    image border, so the shfl edge fixup IS the zeros-padding.
//  - Channel pairs packed as v2f (v_pk ops); math per R3 (3-tap hat
//    weights + Q - S^2/3 variance), VALU ~11us << ~27us memory floor.

#define B_ 4
#define C_ 32
#define H_ 256
#define W_ 256
#define D_ 9
#define G_ 8
#define CPG 4
#define HW_ (H_ * W_)

typedef float v2f __attribute__((ext_vector_type(2)));
typedef float v4f __attribute__((ext_vector_type(4)));

static __device__ __forceinline__ v2f sp(float x) { v2f r; r.x = x; r.y = x; return r; }

__global__ __launch_bounds__(256) void cost_volume_kernel(
    const float* __restrict__ fref,
    const float* __restrict__ fls,
    const float* __restrict__ frs,
    const float* __restrict__ disp0,
    float* __restrict__ out)
{
    const float kRes[D_] = {-0.4f, -0.3f, -0.2f, -0.1f, 0.0f,
                             0.1f,  0.2f,  0.3f,  0.4f};

    const int bid = blockIdx.x;
    const int g = bid & (G_ - 1);
    const int t = bid >> 3;
    const int b = t >> 6;
    const int h = ((t & 63) << 2) | ((int)threadIdx.x >> 6);  // wave = row
    const int lane = (int)threadIdx.x & 63;
    const int w0 = lane << 2;                                  // pixels w0..w0+3

    const v4f dsp = *(const v4f*)(disp0 + (size_t)((b * H_ + h) * W_ + w0));

    // ---- per-pixel lerp setup (disp in [0,1), res in [-0.4,0.4]) ----
    // Left taps x in [w-1, w+2] (rel in {-1,0}); right taps x in [w-2, w+1]
    // (rel in {-2,-1}). Window wl[j] = x = w0-2+j, wr likewise.
    float a1l[4], a1r[4];
    bool sl[4], sr[4];
    #pragma unroll
    for (int p = 0; p < 4; ++p) {
        const int w = w0 + p;
        const float wf = (float)w;
        const float dv = dsp[p];
        const float s0 = wf + dv;
        int rl = (int)floorf(s0 - 0.4f) - w;
        rl = rl < -1 ? -1 : (rl > 0 ? 0 : rl);
        sl[p] = (rl == 0);
        a1l[p] = (s0 - (float)(w + rl)) - 1.0f;
        const float s1 = wf - dv;
        int rr = (int)floorf(s1 - 0.4f) - w;
        rr = rr < -2 ? -2 : (rr > -1 ? -1 : rr);
        sr[p] = (rr == -1);
        a1r[p] = (s1 - (float)(w + rr)) - 1.0f;
    }

    float acc[4][D_];
    #pragma unroll
    for (int p = 0; p < 4; ++p)
        #pragma unroll
        for (int d = 0; d < D_; ++d) acc[p][d] = 0.0f;
    float frq[4] = {0.f, 0.f, 0.f, 0.f};

    const size_t rowbase = (size_t)(b * C_ + g * CPG) * HW_
                         + (size_t)h * W_ + (size_t)w0;

    const bool q0  = (lane == 0);    // left image border: x=-2,-1 -> 0
    const bool q63 = (lane == 63);   // right image border: x=256,257 -> 0

    #pragma unroll
    for (int pp = 0; pp < 2; ++pp) {                 // channel pairs
        const size_t cb = rowbase + (size_t)(2 * pp) * HW_;
        const v4f La = *(const v4f*)(fls  + cb);
        const v4f Lb = *(const v4f*)(fls  + cb + HW_);
        const v4f Ra = *(const v4f*)(frs  + cb);
        const v4f Rb = *(const v4f*)(frs  + cb + HW_);
        const v4f Fa = *(const v4f*)(fref + cb);
        const v4f Fb = *(const v4f*)(fref + cb + HW_);

        auto up = [&](float a) -> float {
            float s = __shfl_up(a, 1);  return q0  ? 0.0f : s;
        };
        auto dn = [&](float a) -> float {
            float s = __shfl_down(a, 1); return q63 ? 0.0f : s;
        };

        // windows packed over the channel pair; wl[j]=x(w0-2+j), j=1..7;
        // wr[j], j=0..6. (wl[0], wr[7] never referenced.)
        v2f wl[8], wr[7];
        wl[1].x = up(La.w); wl[1].y = up(Lb.w);
        wl[2].x = La.x;     wl[2].y = Lb.x;
        wl[3].x = La.y;     wl[3].y = Lb.y;
        wl[4].x = La.z;     wl[4].y = Lb.z;
        wl[5].x = La.w;     wl[5].y = Lb.w;
        wl[6].x = dn(La.x); wl[6].y = dn(Lb.x);
        wl[7].x = dn(La.y); wl[7].y = dn(Lb.y);

        wr[0].x = up(Ra.z); wr[0].y = up(Rb.z);
        wr[1].x = up(Ra.w); wr[1].y = up(Rb.w);
        wr[2].x = Ra.x;     wr[2].y = Rb.x;
        wr[3].x = Ra.y;     wr[3].y = Rb.y;
        wr[4].x = Ra.z;     wr[4].y = Rb.z;
        wr[5].x = Ra.w;     wr[5].y = Rb.w;
        wr[6].x = dn(Ra.x); wr[6].y = dn(Rb.x);

        v2f frp[4];
        frp[0].x = Fa.x; frp[0].y = Fb.x;
        frp[1].x = Fa.y; frp[1].y = Fb.y;
        frp[2].x = Fa.z; frp[2].y = Fb.z;
        frp[3].x = Fa.w; frp[3].y = Fb.w;

        #pragma unroll
        for (int p = 0; p < 4; ++p) {
            frq[p] += frp[p].x * frp[p].x + frp[p].y * frp[p].y;
            // 3 taps/side selected by rel (compile-time window indices)
            const v2f tl0 = sl[p] ? wl[p + 2] : wl[p + 1];
            const v2f tl1 = sl[p] ? wl[p + 3] : wl[p + 2];
            const v2f tl2 = sl[p] ? wl[p + 4] : wl[p + 3];
            const v2f tr0 = sr[p] ? wr[p + 1] : wr[p + 0];
            const v2f tr1 = sr[p] ? wr[p + 2] : wr[p + 1];
            const v2f tr2 = sr[p] ? wr[p + 3] : wr[p + 2];
            const v2f fr2 = frp[p];
            #pragma unroll
            for (int d = 0; d < D_; ++d) {
                const float tlw = a1l[p] + kRes[d];
                const float W0l = fmaxf(-tlw, 0.0f);
                const float W1l = 1.0f - fabsf(tlw);
                const float W2l = fmaxf(tlw, 0.0f);
                const float trw = a1r[p] - kRes[d];
                const float W0r = fmaxf(-trw, 0.0f);
                const float W1r = 1.0f - fabsf(trw);
                const float W2r = fmaxf(trw, 0.0f);

                v2f wlv = tl0 * sp(W0l) + tl1 * sp(W1l) + tl2 * sp(W2l);
                v2f wrv = tr0 * sp(W0r) + tr1 * sp(W1r) + tr2 * sp(W2r);
                v2f Sv  = wlv + wrv + fr2;
                v2f c2  = wlv * wlv + wrv * wrv - Sv * Sv * sp(1.0f / 3.0f);
                acc[p][d] += c2.x + c2.y;
            }
        }
    }

    const size_t obase = ((size_t)(b * G_ + g) * D_) * HW_
                       + (size_t)h * W_ + (size_t)w0;
    #pragma unroll
    for (int d = 0; d < D_; ++d) {
        v4f o;
        o.x = (acc[0][d] + frq[0]) * (1.0f / 12.0f);
        o.y = (acc[1][d] + frq[1]) * (1.0f / 12.0f);
        o.z = (acc[2][d] + frq[2]) * (1.0f / 12.0f);
        o.w = (acc[3][d] + frq[3]) * (1.0f / 12.0f);
        __builtin_nontemporal_store(o, (v4f*)(out + obase + (size_t)d * HW_));
    }
}

extern "C" void kernel_launch(void* const* d_in, const int* in_sizes, int n_in,
                              void* d_out, int out_size, void* d_ws, size_t ws_size,
                              hipStream_t stream) {
    const float* fref  = (const float*)d_in[0];
    const float* fls   = (const float*)d_in[1];
    const float* frs   = (const float*)d_in[2];
    const float* disp0 = (const float*)d_in[3];
    float* out = (float*)d_out;

    dim3 grid(B_ * G_ * (H_ / 4));   // 2048 blocks; wave = one row
    dim3 block(256);
    cost_volume_kernel<<<grid, block, 0, stream>>>(fref, fls, frs, disp0, out);
}